// Round 3
// baseline (2804.270 us; speedup 1.0000x reference)
//
#include <hip/hip_runtime.h>

typedef long long ll;
typedef __bf16 bf16x8 __attribute__((ext_vector_type(8)));
typedef float f32x4 __attribute__((ext_vector_type(4)));

#define T 2048
#define Dm 1024
#define DFF 4096
#define SPK 512
#define MCH 512      // DFF chunk for MoE plane staging (8 chunks)

// ---------------- workspace offsets (in floats) ----------------
// Phase 1 (attn): xn,q,k,v,av live. Phase 2 (MoE): those regions are re-cut
// into bf16 plane buffers + y. x1 live throughout; x2n region becomes H planes.
static const ll OFF_XN    = 0;          // 2048*1024
static const ll OFF_Q     = 2097152;    // 2048*1024
static const ll OFF_K     = 4194304;    // 2048*1024
static const ll OFF_V     = 6291456;    // 2048*1024
static const ll OFF_AV    = 8388608;    // 2048*1024
static const ll OFF_X1    = 10485760;   // 2048*1024  (live to the end)
static const ll OFF_X2N   = 12582912;   // 2048*1024  (dead after router+split)
static const ll OFF_QI    = 14680064;   // 2048*256
static const ll OFF_KI    = 15204352;   // 2048*64
static const ll OFF_HW    = 15335424;   // 2048*4
static const ll OFF_PROBS = 15343616;   // 2048*8
static const ll OFF_GATES = 15360000;   // 2048*2
static const ll OFF_TOPI  = 15364096;   // 2048*2 int
static const ll OFF_PTOK  = 15368192;   // 5120 int
static const ll OFF_PGATE = 15373312;   // 5120
static const ll OFF_TOKP  = 15378432;   // 2048*2 int
static const ll OFF_CNT   = 15382528;   // 8 int   -- memset-0 region starts here
static const ll OFF_PSUM  = 15382536;   // 8 float
static const ll OFF_OFFS  = 15382544;   // 9 int
static const ll OFF_CURS  = 15382560;   // 8 int   -- memset-0 region = 64 floats
static const ll OFF_SELI  = 15382592;   // 2048*512 int
static const ll OFF_SELC  = 16431168;   // 2048 int
// total ws = 16433216 floats = ~62.7 MiB (unchanged)
// --- MoE-phase aliases (exact fits, verified):
static const ll OFF_Y2    = 0;          // 4096*1024 fp32            -> 4194304
static const ll OFF_WPH   = 4194304;    // 8*512*1024 bf16 = 2097152 -> 6291456
static const ll OFF_WPM   = 6291456;    // 8*512*1024 bf16           -> 8388608
static const ll OFF_XH    = 8388608;    // 2048*1024 bf16 = 1048576  -> 9437184
static const ll OFF_XM    = 9437184;    // 2048*1024 bf16            -> 10485760 (=X1)
static const ll OFF_HH    = 12582912;   // 4096*512 bf16 = 1048576   -> 13631488
static const ll OFF_HM    = 13631488;   // 4096*512 bf16             -> 14680064 (=QI)

// ---------------- RMSNorm ----------------
__global__ __launch_bounds__(256) void rmsnorm_k(const float* __restrict__ x,
                                                 const float* __restrict__ w,
                                                 float* __restrict__ o) {
    int t = blockIdx.x, tid = threadIdx.x;
    __shared__ float red[4];
    float4 xv = ((const float4*)(x + (ll)t * Dm))[tid];
    float ss = xv.x * xv.x + xv.y * xv.y + xv.z * xv.z + xv.w * xv.w;
#pragma unroll
    for (int off = 32; off >= 1; off >>= 1) ss += __shfl_xor(ss, off);
    int lane = tid & 63, wv = tid >> 6;
    if (lane == 0) red[wv] = ss;
    __syncthreads();
    float tot = red[0] + red[1] + red[2] + red[3];
    float sc = 1.0f / sqrtf(tot * (1.0f / 1024.0f) + 1e-6f);
    float4 wv4 = ((const float4*)w)[tid];
    float4 ov;
    ov.x = xv.x * sc * wv4.x; ov.y = xv.y * sc * wv4.y;
    ov.z = xv.z * sc * wv4.z; ov.w = xv.w * sc * wv4.w;
    ((float4*)(o + (ll)t * Dm))[tid] = ov;
}

// ---------------- generic tiled fp32 GEMM (indexer path: bit-stable) ----------------
__global__ __launch_bounds__(256) void gemm_k(
    const float* __restrict__ A, int lda,
    const float* __restrict__ B, int ldb, ll ebB,
    float* __restrict__ C, int ldc,
    const float* __restrict__ bias, int ebBias,
    const float* __restrict__ resid,
    const int* __restrict__ gather,
    const int* __restrict__ gcnt, const int* __restrict__ goff,
    int N, int K, int flags) {
    int e = blockIdx.z;
    int m0, mvalid;
    if (gcnt) {
        int cnt = gcnt[e];
        mvalid = cnt - blockIdx.y * 128;
        if (mvalid <= 0) return;
        if (mvalid > 128) mvalid = 128;
        m0 = goff[e] + blockIdx.y * 128;
    } else {
        m0 = blockIdx.y * 128; mvalid = 128;
    }
    int n0 = blockIdx.x * 64;
    const float* Bp = B + (ll)e * ebB;
    __shared__ float As[8][132];
    __shared__ float Bs[8][64];
    int tid = threadIdx.x;
    int tx = tid & 15, ty = tid >> 4;
    int arow = tid >> 1, ak = (tid & 1) * 4;
    int brow = tid >> 4, bn = (tid & 15) * 4;
    ll aRow;
    int asrc = (arow < mvalid) ? arow : 0;
    if (gather) aRow = gather[m0 + asrc]; else aRow = m0 + asrc;
    const float* Aptr = A + aRow * (ll)lda + ak;
    bool bin = (tid < 128) && ((n0 + bn) < N);
    const float* Bptr0 = Bp + n0 + bn;
    float acc[8][4];
#pragma unroll
    for (int r = 0; r < 8; r++)
#pragma unroll
        for (int c = 0; c < 4; c++) acc[r][c] = 0.0f;

    for (int k0 = 0; k0 < K; k0 += 8) {
        float4 a4 = *(const float4*)(Aptr + k0);
        float4 b4 = make_float4(0.f, 0.f, 0.f, 0.f);
        if (bin) b4 = *(const float4*)(Bptr0 + (ll)(k0 + brow) * ldb);
        As[ak + 0][arow] = a4.x; As[ak + 1][arow] = a4.y;
        As[ak + 2][arow] = a4.z; As[ak + 3][arow] = a4.w;
        if (tid < 128) *(float4*)&Bs[brow][bn] = b4;
        __syncthreads();
#pragma unroll
        for (int kk = 0; kk < 8; kk++) {
            float4 a0 = *(const float4*)&As[kk][ty * 8];
            float4 a1 = *(const float4*)&As[kk][ty * 8 + 4];
            float4 b0 = *(const float4*)&Bs[kk][tx * 4];
            float aa[8] = {a0.x, a0.y, a0.z, a0.w, a1.x, a1.y, a1.z, a1.w};
            float bb[4] = {b0.x, b0.y, b0.z, b0.w};
#pragma unroll
            for (int r = 0; r < 8; r++)
#pragma unroll
                for (int c = 0; c < 4; c++)
                    acc[r][c] = fmaf(aa[r], bb[c], acc[r][c]);
        }
        __syncthreads();
    }
#pragma unroll
    for (int r = 0; r < 8; r++) {
        int i = ty * 8 + r;
        if (i >= mvalid) continue;
        ll gm = (ll)(m0 + i);
#pragma unroll
        for (int c = 0; c < 4; c++) {
            int j = n0 + tx * 4 + c;
            if (j >= N) continue;
            float vv = acc[r][c];
            if (flags & 1) vv += bias[(ll)e * ebBias + j];
            if (flags & 2) {
                float g = vv;
                vv = 0.5f * g * (1.0f + tanhf(0.7978845608028654f * (g + 0.044715f * g * g * g)));
            }
            if (flags & 4) vv += resid[gm * ldc + j];
            if (flags & 8) vv += C[gm * ldc + j];
            C[gm * ldc + j] = vv;
        }
    }
}

// ---------------- split helpers ----------------
__device__ __forceinline__ void splitf(float x, unsigned short& h, unsigned short& m) {
    unsigned u = __float_as_uint(x);
    unsigned hv = u & 0xFFFF0000u;
    float r = x - __uint_as_float(hv);
    h = (unsigned short)(hv >> 16);
    m = (unsigned short)(__float_as_uint(r) >> 16);
}

__device__ __forceinline__ void split2(float x0, float x1,
                                       unsigned& h, unsigned& m, unsigned& l) {
    unsigned u0 = __float_as_uint(x0), u1 = __float_as_uint(x1);
    unsigned h0 = u0 & 0xFFFF0000u, h1 = u1 & 0xFFFF0000u;
    float r0 = x0 - __uint_as_float(h0);
    float r1 = x1 - __uint_as_float(h1);
    unsigned v0 = __float_as_uint(r0), v1 = __float_as_uint(r1);
    unsigned q0 = v0 & 0xFFFF0000u, q1 = v1 & 0xFFFF0000u;
    float s0 = r0 - __uint_as_float(q0);
    float s1 = r1 - __uint_as_float(q1);
    h = (h0 >> 16) | h1;
    m = (q0 >> 16) | q1;
    l = (__float_as_uint(s0) >> 16) | (__float_as_uint(s1) & 0xFFFF0000u);
}

__device__ __forceinline__ void st16(unsigned short* dst, const unsigned* p) {
    uint4 u; u.x = p[0]; u.y = p[1]; u.z = p[2]; u.w = p[3];
    *(uint4*)dst = u;
}

// elementwise fp32 -> 2 bf16 planes (same layout)
__global__ __launch_bounds__(256) void split_k(const float* __restrict__ src,
                                               unsigned short* __restrict__ dh,
                                               unsigned short* __restrict__ dm) {
    int i = (blockIdx.x * 256 + threadIdx.x) * 4;
    float4 v = *(const float4*)(src + i);
    ushort4 h4, m4;
    splitf(v.x, h4.x, m4.x); splitf(v.y, h4.y, m4.y);
    splitf(v.z, h4.z, m4.z); splitf(v.w, h4.w, m4.w);
    *(ushort4*)&dh[i] = h4;
    *(ushort4*)&dm[i] = m4;
}

// transpose+split: out[e][n][k] = src[e][k][n] for a [K][N] slice, as 2 bf16 planes
__global__ __launch_bounds__(256) void tsplit_k(const float* __restrict__ src, int ldsrc, ll ebS,
                                                unsigned short* __restrict__ dh,
                                                unsigned short* __restrict__ dm, ll ebD,
                                                int K, int N) {
    int e = blockIdx.z;
    const float* S = src + (ll)e * ebS;
    unsigned short* Dh = dh + (ll)e * ebD;
    unsigned short* Dmm = dm + (ll)e * ebD;
    __shared__ float tile[64][65];
    int k0 = blockIdx.y * 64, n0 = blockIdx.x * 64;
    int tid = threadIdx.x, tx = tid & 15, ty = tid >> 4;
#pragma unroll
    for (int i = 0; i < 4; i++) {
        int r = ty + i * 16;
        float4 v = *(const float4*)(S + (ll)(k0 + r) * ldsrc + n0 + tx * 4);
        tile[r][tx * 4 + 0] = v.x; tile[r][tx * 4 + 1] = v.y;
        tile[r][tx * 4 + 2] = v.z; tile[r][tx * 4 + 3] = v.w;
    }
    __syncthreads();
#pragma unroll
    for (int i = 0; i < 4; i++) {
        int r = ty + i * 16;   // n index
        ushort4 h4, m4;
        splitf(tile[tx * 4 + 0][r], h4.x, m4.x);
        splitf(tile[tx * 4 + 1][r], h4.y, m4.y);
        splitf(tile[tx * 4 + 2][r], h4.z, m4.z);
        splitf(tile[tx * 4 + 3][r], h4.w, m4.w);
        ll o = (ll)(n0 + r) * K + k0 + tx * 4;
        *(ushort4*)&Dh[o] = h4;
        *(ushort4*)&Dmm[o] = m4;
    }
}

// ---------------- plane GEMM: 2-plane bf16 MFMA, pre-split inputs ----------------
// C = (Ah+Am)·(Bh+Bm) via hh+hm+mh.  A planes [M][K], B planes [e][N][K].
// Grouped rows via gcnt/goff (+optional gather). If Ch!=null: write bf16 hi/m
// planes of the (bias/gelu'd) result instead of fp32 C.
// flags: 1=+bias  2=gelu  8=accumulate into C
__global__ __launch_bounds__(256) void pgemm_k(
    const unsigned short* __restrict__ Ah, const unsigned short* __restrict__ Am, int lda,
    const unsigned short* __restrict__ Bh, const unsigned short* __restrict__ Bm, ll ebB, int ldb,
    float* __restrict__ C, int ldc,
    unsigned short* __restrict__ Ch, unsigned short* __restrict__ Cm, int ldch,
    const float* __restrict__ bias, int ebBias,
    const int* __restrict__ gather,
    const int* __restrict__ gcnt, const int* __restrict__ goff,
    int N, int K, int flags) {
    int e = blockIdx.z;
    int cnt = gcnt[e];
    int mvalid = cnt - blockIdx.y * 128;
    if (mvalid <= 0) return;
    if (mvalid > 128) mvalid = 128;
    int m0 = goff[e] + blockIdx.y * 128;
    int n0 = blockIdx.x * 128;
    const unsigned short* BpH = Bh + (ll)e * ebB;
    const unsigned short* BpM = Bm + (ll)e * ebB;

    // rows padded 32->40 ushorts (80B): breaks the stride-64B frag-read bank alias
    __shared__ __align__(16) unsigned short Ash[128][40], Asm[128][40];
    __shared__ __align__(16) unsigned short Bsh[128][40], Bsm[128][40];

    int tid = threadIdx.x;
    int arow = tid >> 1, ak = (tid & 1) * 16;
    int asrc = (arow < mvalid) ? arow : 0;
    ll aRowG = gather ? (ll)gather[m0 + asrc] : (ll)(m0 + asrc);
    const unsigned short* ApH = Ah + aRowG * (ll)lda + ak;
    const unsigned short* ApM = Am + aRowG * (ll)lda + ak;
    int bn = tid & 127, bk = (tid >> 7) * 16;
    const unsigned short* BrH = BpH + (ll)(n0 + bn) * ldb + bk;
    const unsigned short* BrM = BpM + (ll)(n0 + bn) * ldb + bk;

    int lane = tid & 63, wid = tid >> 6;
    int wr = (wid >> 1) * 64, wc = (wid & 1) * 64;
    int fr = lane & 15, fk = (lane >> 4) * 8;

    f32x4 acc[4][4];
    f32x4 zero4 = {0.0f, 0.0f, 0.0f, 0.0f};
#pragma unroll
    for (int i = 0; i < 4; i++)
#pragma unroll
        for (int j = 0; j < 4; j++) acc[i][j] = zero4;

    for (int k0 = 0; k0 < K; k0 += 32) {
        uint4 a0 = *(const uint4*)(ApH + k0);
        uint4 a1 = *(const uint4*)(ApH + k0 + 8);
        uint4 a2 = *(const uint4*)(ApM + k0);
        uint4 a3 = *(const uint4*)(ApM + k0 + 8);
        uint4 b0 = *(const uint4*)(BrH + k0);
        uint4 b1 = *(const uint4*)(BrH + k0 + 8);
        uint4 b2 = *(const uint4*)(BrM + k0);
        uint4 b3 = *(const uint4*)(BrM + k0 + 8);
        __syncthreads();   // prev iteration's frag reads complete
        *(uint4*)&Ash[arow][ak] = a0;  *(uint4*)&Ash[arow][ak + 8] = a1;
        *(uint4*)&Asm[arow][ak] = a2;  *(uint4*)&Asm[arow][ak + 8] = a3;
        *(uint4*)&Bsh[bn][bk] = b0;    *(uint4*)&Bsh[bn][bk + 8] = b1;
        *(uint4*)&Bsm[bn][bk] = b2;    *(uint4*)&Bsm[bn][bk + 8] = b3;
        __syncthreads();

        bf16x8 Afh[4], Afm[4];
#pragma unroll
        for (int mi = 0; mi < 4; mi++) {
            int rr = wr + mi * 16 + fr;
            Afh[mi] = *(const bf16x8*)&Ash[rr][fk];
            Afm[mi] = *(const bf16x8*)&Asm[rr][fk];
        }
#pragma unroll
        for (int ni = 0; ni < 4; ni++) {
            int rc = wc + ni * 16 + fr;
            bf16x8 bh = *(const bf16x8*)&Bsh[rc][fk];
            bf16x8 bm = *(const bf16x8*)&Bsm[rc][fk];
#pragma unroll
            for (int mi = 0; mi < 4; mi++) {
                f32x4 c = acc[mi][ni];
                c = __builtin_amdgcn_mfma_f32_16x16x32_bf16(Afh[mi], bh, c, 0, 0, 0);
                c = __builtin_amdgcn_mfma_f32_16x16x32_bf16(Afh[mi], bm, c, 0, 0, 0);
                c = __builtin_amdgcn_mfma_f32_16x16x32_bf16(Afm[mi], bh, c, 0, 0, 0);
                acc[mi][ni] = c;
            }
        }
    }

    int frow = (lane >> 4) * 4;
#pragma unroll
    for (int ni = 0; ni < 4; ni++) {
        int j = n0 + wc + ni * 16 + fr;
        float bv = (flags & 1) ? bias[(ll)e * ebBias + j] : 0.0f;
#pragma unroll
        for (int mi = 0; mi < 4; mi++) {
            int ib = wr + mi * 16 + frow;
#pragma unroll
            for (int r = 0; r < 4; r++) {
                int i = ib + r;
                if (i >= mvalid) continue;
                ll gm = (ll)(m0 + i);
                float vv = acc[mi][ni][r] + bv;
                if (flags & 2) {
                    float g = vv;
                    vv = 0.5f * g * (1.0f + tanhf(0.7978845608028654f * (g + 0.044715f * g * g * g)));
                }
                if (Ch) {
                    unsigned short hh, mm;
                    splitf(vv, hh, mm);
                    Ch[gm * ldch + j] = hh;
                    Cm[gm * ldch + j] = mm;
                } else {
                    if (flags & 8) vv += C[gm * ldc + j];
                    C[gm * ldc + j] = vv;
                }
            }
        }
    }
}

// ---------------- NS=3 split MFMA GEMM (QKV / wo: selection-safe, err ~2^-22) ----------------
template<int NS>
__global__ __launch_bounds__(256) void mgemm_k(
    const float* __restrict__ A, int lda,
    const float* __restrict__ B, int ldb, ll ebB,
    const float* __restrict__ B2, const float* __restrict__ B3, ll ebC,
    float* __restrict__ C, int ldc,
    const float* __restrict__ bias, int ebBias,
    const float* __restrict__ resid,
    const int* __restrict__ gather,
    const int* __restrict__ gcnt, const int* __restrict__ goff,
    int N, int K, int flags) {
    int e = blockIdx.z;
    int m0, mvalid;
    const float* Bp;
    float* Cp = C;
    if (gcnt) {
        int cnt = gcnt[e];
        mvalid = cnt - blockIdx.y * 128;
        if (mvalid <= 0) return;
        if (mvalid > 128) mvalid = 128;
        m0 = goff[e] + blockIdx.y * 128;
        Bp = B + (ll)e * ebB;
    } else {
        m0 = blockIdx.y * 128; mvalid = 128;
        Bp = (B2 == nullptr || e == 0) ? B : (e == 1 ? B2 : B3);
        Cp = C + (ll)e * ebC;
    }
    int n0 = blockIdx.x * 128;

    __shared__ __align__(16) unsigned short Ah[128][32], Amd[128][32];
    __shared__ __align__(16) unsigned short Bh[128][32], Bmd[128][32];
    __shared__ __align__(16) unsigned short Alo[NS == 3 ? 128 : 1][32];
    __shared__ __align__(16) unsigned short Blo[NS == 3 ? 128 : 1][32];

    int tid = threadIdx.x;
    int arow = tid >> 1, apart = (tid & 1) * 16;
    int asrc = (arow < mvalid) ? arow : 0;
    ll aRowG = gather ? (ll)gather[m0 + asrc] : (ll)(m0 + asrc);
    const float* Ap = A + aRowG * (ll)lda + apart;
    int bn = tid & 127, bkh = (tid >> 7) * 16;
    const float* Bpp = Bp + (ll)bkh * ldb + n0 + bn;

    int lane = tid & 63, wid = tid >> 6;
    int wr = (wid >> 1) * 64, wc = (wid & 1) * 64;
    int fr = lane & 15, fk = (lane >> 4) * 8;

    f32x4 acc[4][4];
    f32x4 zero4 = {0.0f, 0.0f, 0.0f, 0.0f};
#pragma unroll
    for (int i = 0; i < 4; i++)
#pragma unroll
        for (int j = 0; j < 4; j++) acc[i][j] = zero4;

    for (int k0 = 0; k0 < K; k0 += 32) {
        const float4* ap4 = (const float4*)(Ap + k0);
        float4 a4[4];
#pragma unroll
        for (int i = 0; i < 4; i++) a4[i] = ap4[i];
        float bbuf[16];
        const float* bp = Bpp + (ll)k0 * ldb;
#pragma unroll
        for (int i = 0; i < 16; i++) bbuf[i] = bp[(ll)i * ldb];

        __syncthreads();

        unsigned ph[8], pm[8], pl[8];
        split2(a4[0].x, a4[0].y, ph[0], pm[0], pl[0]);
        split2(a4[0].z, a4[0].w, ph[1], pm[1], pl[1]);
        split2(a4[1].x, a4[1].y, ph[2], pm[2], pl[2]);
        split2(a4[1].z, a4[1].w, ph[3], pm[3], pl[3]);
        split2(a4[2].x, a4[2].y, ph[4], pm[4], pl[4]);
        split2(a4[2].z, a4[2].w, ph[5], pm[5], pl[5]);
        split2(a4[3].x, a4[3].y, ph[6], pm[6], pl[6]);
        split2(a4[3].z, a4[3].w, ph[7], pm[7], pl[7]);
        st16(&Ah[arow][apart], ph);  st16(&Ah[arow][apart + 8], ph + 4);
        st16(&Amd[arow][apart], pm); st16(&Amd[arow][apart + 8], pm + 4);
        if constexpr (NS == 3) {
            st16(&Alo[arow][apart], pl); st16(&Alo[arow][apart + 8], pl + 4);
        }

        split2(bbuf[0],  bbuf[1],  ph[0], pm[0], pl[0]);
        split2(bbuf[2],  bbuf[3],  ph[1], pm[1], pl[1]);
        split2(bbuf[4],  bbuf[5],  ph[2], pm[2], pl[2]);
        split2(bbuf[6],  bbuf[7],  ph[3], pm[3], pl[3]);
        split2(bbuf[8],  bbuf[9],  ph[4], pm[4], pl[4]);
        split2(bbuf[10], bbuf[11], ph[5], pm[5], pl[5]);
        split2(bbuf[12], bbuf[13], ph[6], pm[6], pl[6]);
        split2(bbuf[14], bbuf[15], ph[7], pm[7], pl[7]);
        st16(&Bh[bn][bkh], ph);  st16(&Bh[bn][bkh + 8], ph + 4);
        st16(&Bmd[bn][bkh], pm); st16(&Bmd[bn][bkh + 8], pm + 4);
        if constexpr (NS == 3) {
            st16(&Blo[bn][bkh], pl); st16(&Blo[bn][bkh + 8], pl + 4);
        }

        __syncthreads();

        bf16x8 Afh[4], Afm[4], Afl[4];
#pragma unroll
        for (int mi = 0; mi < 4; mi++) {
            int rr = wr + mi * 16 + fr;
            Afh[mi] = *(const bf16x8*)&Ah[rr][fk];
            Afm[mi] = *(const bf16x8*)&Amd[rr][fk];
            if constexpr (NS == 3) Afl[mi] = *(const bf16x8*)&Alo[rr][fk];
        }
#pragma unroll
        for (int ni = 0; ni < 4; ni++) {
            int rc = wc + ni * 16 + fr;
            bf16x8 bh = *(const bf16x8*)&Bh[rc][fk];
            bf16x8 bm = *(const bf16x8*)&Bmd[rc][fk];
            if constexpr (NS == 3) {
                bf16x8 bl = *(const bf16x8*)&Blo[rc][fk];
#pragma unroll
                for (int mi = 0; mi < 4; mi++) {
                    f32x4 c = acc[mi][ni];
                    c = __builtin_amdgcn_mfma_f32_16x16x32_bf16(Afh[mi], bh, c, 0, 0, 0);
                    c = __builtin_amdgcn_mfma_f32_16x16x32_bf16(Afh[mi], bm, c, 0, 0, 0);
                    c = __builtin_amdgcn_mfma_f32_16x16x32_bf16(Afm[mi], bh, c, 0, 0, 0);
                    c = __builtin_amdgcn_mfma_f32_16x16x32_bf16(Afh[mi], bl, c, 0, 0, 0);
                    c = __builtin_amdgcn_mfma_f32_16x16x32_bf16(Afm[mi], bm, c, 0, 0, 0);
                    c = __builtin_amdgcn_mfma_f32_16x16x32_bf16(Afl[mi], bh, c, 0, 0, 0);
                    acc[mi][ni] = c;
                }
            } else {
#pragma unroll
                for (int mi = 0; mi < 4; mi++) {
                    f32x4 c = acc[mi][ni];
                    c = __builtin_amdgcn_mfma_f32_16x16x32_bf16(Afh[mi], bh, c, 0, 0, 0);
                    c = __builtin_amdgcn_mfma_f32_16x16x32_bf16(Afh[mi], bm, c, 0, 0, 0);
                    c = __builtin_amdgcn_mfma_f32_16x16x32_bf16(Afm[mi], bh, c, 0, 0, 0);
                    acc[mi][ni] = c;
                }
            }
        }
    }

    int frow = (lane >> 4) * 4;
#pragma unroll
    for (int ni = 0; ni < 4; ni++) {
        int j = n0 + wc + ni * 16 + fr;
        float bv = (flags & 1) ? bias[(ll)e * ebBias + j] : 0.0f;
#pragma unroll
        for (int mi = 0; mi < 4; mi++) {
            int ib = wr + mi * 16 + frow;
#pragma unroll
            for (int r = 0; r < 4; r++) {
                int i = ib + r;
                if (i >= mvalid) continue;
                ll gm = (ll)(m0 + i);
                float vv = acc[mi][ni][r] + bv;
                if (flags & 2) {
                    float g = vv;
                    vv = 0.5f * g * (1.0f + tanhf(0.7978845608028654f * (g + 0.044715f * g * g * g)));
                }
                if (flags & 4) vv += resid[gm * ldc + j];
                if (flags & 8) vv += Cp[gm * ldc + j];
                Cp[gm * ldc + j] = vv;
            }
        }
    }
}

// ---------------- small-N projection (wave per token) ----------------
__global__ __launch_bounds__(256) void smalln_k(const float* __restrict__ A,
                                                const float* __restrict__ W,
                                                float* __restrict__ Co, int N) {
    int wv = (blockIdx.x * 256 + threadIdx.x) >> 6;
    int lane = threadIdx.x & 63;
    if (wv >= T) return;
    const float* a = A + (ll)wv * Dm;
    float xs[16];
#pragma unroll
    for (int i = 0; i < 16; i++) xs[i] = a[lane + 64 * i];
    for (int n = 0; n < N; n++) {
        float s = 0.0f;
#pragma unroll
        for (int i = 0; i < 16; i++) s = fmaf(xs[i], W[(ll)(lane + 64 * i) * N + n], s);
#pragma unroll
        for (int off = 32; off >= 1; off >>= 1) s += __shfl_xor(s, off);
        if (lane == 0) Co[(ll)wv * N + n] = s;
    }
}

// ---------------- RoPE (q and k in place) ----------------
__global__ __launch_bounds__(256) void rope_k(float* __restrict__ q, float* __restrict__ k) {
    int i = blockIdx.x * 256 + threadIdx.x;   // T*16*32
    int d = i & 31; int h = (i >> 5) & 15; int t = i >> 9;
    float inv = powf(10000.0f, -(float)(2 * d) * (1.0f / 64.0f));
    float ang = (float)t * inv;
    float cs = cosf(ang), sn = sinf(ang);
    ll base = (ll)t * Dm + h * 64 + d;
    float a = q[base], b = q[base + 32];
    q[base] = a * cs - b * sn; q[base + 32] = b * cs + a * sn;
    a = k[base]; b = k[base + 32];
    k[base] = a * cs - b * sn; k[base + 32] = b * cs + a * sn;
}

// ---------------- lightning indexer scores (full TxT, unmasked) ----------------
__global__ __launch_bounds__(256) void idx_k(const float* __restrict__ qi,
                                             const float* __restrict__ ki,
                                             const float* __restrict__ hww,
                                             float* __restrict__ out) {
    __shared__ float Aq[64][65];
    __shared__ float Bk[64][65];
    __shared__ float hs[64][4];
    int t0 = blockIdx.y * 64, s0 = blockIdx.x * 64;
    int tid = threadIdx.x;
    int tx = tid & 15, ty = tid >> 4;
    int ty4 = ty * 4, tx4 = tx * 4;
    if (tid < 64) {
#pragma unroll
        for (int e = 0; e < 4; e++) hs[tid][e] = hww[(ll)(t0 + tid) * 4 + e];
    }
#pragma unroll
    for (int it = 0; it < 4; it++) {
        int f4 = tid + it * 256;
        int row = f4 >> 4, c4 = (f4 & 15) * 4;
        float4 kv = *(const float4*)(ki + (ll)(s0 + row) * 64 + c4);
        Bk[row][c4] = kv.x; Bk[row][c4 + 1] = kv.y; Bk[row][c4 + 2] = kv.z; Bk[row][c4 + 3] = kv.w;
    }
    float acc[4][4];
#pragma unroll
    for (int r = 0; r < 4; r++)
#pragma unroll
        for (int c = 0; c < 4; c++) acc[r][c] = 0.0f;

    for (int h = 0; h < 4; h++) {
        __syncthreads();
#pragma unroll
        for (int it = 0; it < 4; it++) {
            int f4 = tid + it * 256;
            int row = f4 >> 4, c4 = (f4 & 15) * 4;
            float4 qv = *(const float4*)(qi + (ll)(t0 + row) * 256 + h * 64 + c4);
            Aq[row][c4] = qv.x; Aq[row][c4 + 1] = qv.y; Aq[row][c4 + 2] = qv.z; Aq[row][c4 + 3] = qv.w;
        }
        __syncthreads();
        float dh[4][4];
#pragma unroll
        for (int r = 0; r < 4; r++)
#pragma unroll
            for (int c = 0; c < 4; c++) dh[r][c] = 0.0f;
#pragma unroll 8
        for (int d = 0; d < 64; d++) {
            float a0 = Aq[ty4 + 0][d], a1 = Aq[ty4 + 1][d], a2 = Aq[ty4 + 2][d], a3 = Aq[ty4 + 3][d];
            float b0 = Bk[tx4 + 0][d], b1 = Bk[tx4 + 1][d], b2 = Bk[tx4 + 2][d], b3 = Bk[tx4 + 3][d];
            dh[0][0] = fmaf(a0, b0, dh[0][0]); dh[0][1] = fmaf(a0, b1, dh[0][1]);
            dh[0][2] = fmaf(a0, b2, dh[0][2]); dh[0][3] = fmaf(a0, b3, dh[0][3]);
            dh[1][0] = fmaf(a1, b0, dh[1][0]); dh[1][1] = fmaf(a1, b1, dh[1][1]);
            dh[1][2] = fmaf(a1, b2, dh[1][2]); dh[1][3] = fmaf(a1, b3, dh[1][3]);
            dh[2][0] = fmaf(a2, b0, dh[2][0]); dh[2][1] = fmaf(a2, b1, dh[2][1]);
            dh[2][2] = fmaf(a2, b2, dh[2][2]); dh[2][3] = fmaf(a2, b3, dh[2][3]);
            dh[3][0] = fmaf(a3, b0, dh[3][0]); dh[3][1] = fmaf(a3, b1, dh[3][1]);
            dh[3][2] = fmaf(a3, b2, dh[3][2]); dh[3][3] = fmaf(a3, b3, dh[3][3]);
        }
#pragma unroll
        for (int r = 0; r < 4; r++) {
            float hv = hs[ty4 + r][h];
#pragma unroll
            for (int c = 0; c < 4; c++)
                acc[r][c] = fmaf(hv, fmaxf(dh[r][c], 0.0f), acc[r][c]);
        }
    }
#pragma unroll
    for (int r = 0; r < 4; r++)
#pragma unroll
        for (int c = 0; c < 4; c++)
            out[(ll)(t0 + ty4 + r) * T + s0 + tx4 + c] = acc[r][c] * 0.125f;
}

// ---------------- exact top-512 per row: 64-bit radix select ----------------
__global__ __launch_bounds__(256) void topk_k(const float* __restrict__ idx,
                                              int* __restrict__ seli,
                                              int* __restrict__ selc) {
    int t = blockIdx.x, tid = threadIdx.x;
    const float* row = idx + (ll)t * T;
    if (t < SPK) {
        for (int s = tid; s <= t; s += 256) seli[(ll)t * SPK + s] = s;
        if (tid == 0) selc[t] = t + 1;
        return;
    }
    __shared__ unsigned int hist[256];
    __shared__ unsigned long long sh_prefix;
    __shared__ int sh_k, sh_cur;
    if (tid == 0) { sh_prefix = 0ULL; sh_k = SPK; sh_cur = 0; }
    for (int p = 7; p >= 0; p--) {
        hist[tid] = 0u;
        __syncthreads();
        unsigned long long prefix = sh_prefix;
        unsigned long long maskhi = (p == 7) ? 0ULL : ((~0ULL) << ((p + 1) * 8));
        for (int s = tid; s <= t; s += 256) {
            unsigned int u = __float_as_uint(row[s]);
            u = (u & 0x80000000u) ? ~u : (u | 0x80000000u);
            unsigned long long key = ((unsigned long long)u << 32) | (unsigned int)(0xFFFFFFFFu - (unsigned int)s);
            if ((key & maskhi) == prefix)
                atomicAdd(&hist[(unsigned int)(key >> (p * 8)) & 0xFFu], 1u);
        }
        __syncthreads();
        if (tid == 0) {
            int rem = sh_k, b;
            for (b = 255; b > 0; b--) {
                int hc = (int)hist[b];
                if (hc >= rem) break;
                rem -= hc;
            }
            sh_prefix = prefix | ((unsigned long long)(unsigned int)b << (p * 8));
            sh_k = rem;
        }
        __syncthreads();
    }
    unsigned long long tau = sh_prefix;
    for (int s = tid; s <= t; s += 256) {
        unsigned int u = __float_as_uint(row[s]);
        u = (u & 0x80000000u) ? ~u : (u | 0x80000000u);
        unsigned long long key = ((unsigned long long)u << 32) | (unsigned int)(0xFFFFFFFFu - (unsigned int)s);
        if (key >= tau) {
            int pos = atomicAdd(&sh_cur, 1);
            seli[(ll)t * SPK + pos] = s;
        }
    }
    __syncthreads();
    if (tid == 0) selc[t] = sh_cur;
}

// ---------------- sparse attention: block per query token, all 16 heads ----------------
__global__ __launch_bounds__(256) void attn_k(const float* __restrict__ q,
                                              const float* __restrict__ k,
                                              const float* __restrict__ v,
                                              const int* __restrict__ seli,
                                              const int* __restrict__ selc,
                                              float* __restrict__ av) {
    int t = blockIdx.x, tid = threadIdx.x;
    __shared__ float qs[1024];
    __shared__ float sc[16 * 513];
    __shared__ int ssel[512];
    int n = selc[t];
    ((float4*)qs)[tid] = ((const float4*)(q + (ll)t * Dm))[tid];
    for (int j = tid; j < n; j += 256) ssel[j] = seli[(ll)t * SPK + j];
    __syncthreads();
    int lane = tid & 63, w = tid >> 6;
    int h = lane >> 2, part = lane & 3;
    const float4* qp = (const float4*)(qs + lane * 16);
    float4 q0 = qp[0], q1 = qp[1], q2 = qp[2], q3 = qp[3];
    for (int j = w; j < n; j += 4) {
        int s = ssel[j];
        const float4* kp = (const float4*)(k + (ll)s * Dm + lane * 16);
        float4 k0 = kp[0], k1 = kp[1], k2 = kp[2], k3 = kp[3];
        float d;
        d  = q0.x * k0.x + q0.y * k0.y + q0.z * k0.z + q0.w * k0.w;
        d += q1.x * k1.x + q1.y * k1.y + q1.z * k1.z + q1.w * k1.w;
        d += q2.x * k2.x + q2.y * k2.y + q2.z * k2.z + q2.w * k2.w;
        d += q3.x * k3.x + q3.y * k3.y + q3.z * k3.z + q3.w * k3.w;
        d += __shfl_xor(d, 1);
        d += __shfl_xor(d, 2);
        if (part == 0) sc[h * 513 + j] = d * 0.125f;
    }
    __syncthreads();
    for (int hh = w * 4; hh < w * 4 + 4; hh++) {
        float m = -3.0e38f;
        for (int j = lane; j < n; j += 64) m = fmaxf(m, sc[hh * 513 + j]);
#pragma unroll
        for (int off = 32; off >= 1; off >>= 1) m = fmaxf(m, __shfl_xor(m, off));
        float ssum = 0.0f;
        for (int j = lane; j < n; j += 64) {
            float p = expf(sc[hh * 513 + j] - m);
            sc[hh * 513 + j] = p; ssum += p;
        }
#pragma unroll
        for (int off = 32; off >= 1; off >>= 1) ssum += __shfl_xor(ssum, off);
        float inv = 1.0f / ssum;
        for (int j = lane; j < n; j += 64) sc[hh * 513 + j] *= inv;
    }
    __syncthreads();
    int base = tid * 4, oh = tid >> 4;
    float ax = 0, ay = 0, az = 0, aw = 0;
    for (int j = 0; j < n; j++) {
        float p = sc[oh * 513 + j];
        float4 vv = *(const float4*)(v + (ll)ssel[j] * Dm + base);
        ax = fmaf(p, vv.x, ax); ay = fmaf(p, vv.y, ay);
        az = fmaf(p, vv.z, az); aw = fmaf(p, vv.w, aw);
    }
    float4 o4; o4.x = ax; o4.y = ay; o4.z = az; o4.w = aw;
    *(float4*)(av + (ll)t * Dm + base) = o4;
}

// ---------------- router: softmax + top2 + aux accumulators ----------------
__global__ __launch_bounds__(256) void router_k(const float* __restrict__ x2n,
                                                const float* __restrict__ rw,
                                                const float* __restrict__ rb,
                                                float* __restrict__ probs,
                                                float* __restrict__ gates,
                                                int* __restrict__ topi,
                                                int* __restrict__ cnt,
                                                float* __restrict__ psum) {
    int wv = (blockIdx.x * 256 + threadIdx.x) >> 6;
    int lane = threadIdx.x & 63;
    if (wv >= T) return;
    const float* a = x2n + (ll)wv * Dm;
    float l[8] = {0, 0, 0, 0, 0, 0, 0, 0};
    for (int i = 0; i < 16; i++) {
        int kk = lane + 64 * i;
        float xk = a[kk];
        const float* rp = rw + (ll)kk * 8;
#pragma unroll
        for (int e = 0; e < 8; e++) l[e] = fmaf(xk, rp[e], l[e]);
    }
#pragma unroll
    for (int e = 0; e < 8; e++) {
#pragma unroll
        for (int off = 32; off >= 1; off >>= 1) l[e] += __shfl_xor(l[e], off);
    }
    if (lane == 0) {
        float m = -3.0e38f;
#pragma unroll
        for (int e = 0; e < 8; e++) { l[e] += rb[e]; m = fmaxf(m, l[e]); }
        float p[8], s = 0.0f;
#pragma unroll
        for (int e = 0; e < 8; e++) { p[e] = expf(l[e] - m); s += p[e]; }
        float invs = 1.0f / s;
#pragma unroll
        for (int e = 0; e < 8; e++) {
            p[e] *= invs;
            probs[(ll)wv * 8 + e] = p[e];
            atomicAdd(&psum[e], p[e]);
        }
        int i1 = 0; float v1 = p[0];
#pragma unroll
        for (int e = 1; e < 8; e++) if (p[e] > v1) { v1 = p[e]; i1 = e; }
        int i2 = -1; float v2 = -1.0f;
#pragma unroll
        for (int e = 0; e < 8; e++) if (e != i1 && p[e] > v2) { v2 = p[e]; i2 = e; }
        float g = 1.0f / (v1 + v2);
        gates[wv * 2] = v1 * g; gates[wv * 2 + 1] = v2 * g;
        topi[wv * 2] = i1; topi[wv * 2 + 1] = i2;
        atomicAdd(&cnt[i1], 1); atomicAdd(&cnt[i2], 1);
    }
}

__global__ void offs_k(const int* __restrict__ cnt, int* __restrict__ offs) {
    if (threadIdx.x == 0 && blockIdx.x == 0) {
        int o = 0;
        for (int e = 0; e < 8; e++) { offs[e] = o; o += cnt[e]; }   // exact, no pad
        offs[8] = o;
    }
}

__global__ __launch_bounds__(256) void scatter_k(const int* __restrict__ topi,
                                                 const float* __restrict__ gates,
                                                 const int* __restrict__ offs,
                                                 int* __restrict__ curs,
                                                 int* __restrict__ ptok,
                                                 float* __restrict__ pgate,
                                                 int* __restrict__ tokp) {
    int tk = blockIdx.x * 256 + threadIdx.x;
    if (tk >= T) return;
    for (int j = 0; j < 2; j++) {
        int e = topi[tk * 2 + j];
        int slot = atomicAdd(&curs[e], 1);
        int idx = offs[e] + slot;
        ptok[idx] = tk;
        pgate[idx] = gates[tk * 2 + j];
        tokp[tk * 2 + j] = idx;
    }
}

__global__ __launch_bounds__(256) void combine_k(const float* __restrict__ x1,
                                                 const float* __restrict__ y,
                                                 const int* __restrict__ tokp,
                                                 const float* __restrict__ pgate,
                                                 float* __restrict__ out) {
    int i = blockIdx.x * 256 + threadIdx.x;   // T*Dm/4
    int tk = i >> 8, d4 = i & 255;
    int p0 = tokp[tk * 2], p1 = tokp[tk * 2 + 1];
    float g0 = pgate[p0], g1 = pgate[p1];
    float4 a = ((const float4*)(x1 + (ll)tk * Dm))[d4];
    float4 y0 = ((const float4*)(y + (ll)p0 * Dm))[d4];
    float4 y1 = ((const float4*)(y + (ll)p1 * Dm))[d4];
    float4 o4;
    o4.x = a.x + g0 * y0.x + g1 * y1.x;
    o4.y = a.y + g0 * y0.y + g1 * y1.y;
    o4.z = a.z + g0 * y0.z + g1 * y1.z;
    o4.w = a.w + g0 * y0.w + g1 * y1.w;
    ((float4*)(out + (ll)tk * Dm))[d4] = o4;
}

__global__ void aux_k(const int* __restrict__ cnt, const float* __restrict__ psum,
                      float* __restrict__ outp) {
    if (threadIdx.x == 0 && blockIdx.x == 0) {
        float s = 0.0f;
        for (int e = 0; e < 8; e++) s += (float)cnt[e] * psum[e];
        outp[0] = 8.0f * s * (1.0f / (2048.0f * 2048.0f));
    }
}

// ---------------- launch ----------------
extern "C" void kernel_launch(void* const* d_in, const int* in_sizes, int n_in,
                              void* d_out, int out_size, void* d_ws, size_t ws_size,
                              hipStream_t stream) {
    const float* x      = (const float*)d_in[0];
    const float* n1w    = (const float*)d_in[1];
    const float* n2w    = (const float*)d_in[2];
    const float* wq_idx = (const float*)d_in[3];
    const float* wk_idx = (const float*)d_in[4];
    const float* w_head = (const float*)d_in[5];
    const float* wq     = (const float*)d_in[6];
    const float* wk     = (const float*)d_in[7];
    const float* wvp    = (const float*)d_in[8];
    const float* wo     = (const float*)d_in[9];
    const float* rw     = (const float*)d_in[10];
    const float* rb     = (const float*)d_in[11];
    const float* w1     = (const float*)d_in[12];
    const float* b1     = (const float*)d_in[13];
    const float* w2     = (const float*)d_in[14];
    const float* b2     = (const float*)d_in[15];

    float* ws = (float*)d_ws;
    float* out  = (float*)d_out;               // [T*Dm]
    float* auxp = out + (ll)T * Dm;            // [1]
    float* idxs = auxp + 1;                    // [T*T]

    float* xn   = ws + OFF_XN;
    float* qb   = ws + OFF_Q;
    float* kb   = ws + OFF_K;
    float* vb   = ws + OFF_V;
    float* av   = ws + OFF_AV;
    float* x1   = ws + OFF_X1;
    float* x2n  = ws + OFF_X2N;
    float* qi   = ws + OFF_QI;
    float* kib  = ws + OFF_KI;
    float* hwb  = ws + OFF_HW;
    float* probs = ws + OFF_PROBS;
    float* gates = ws + OFF_GATES;
    int*   topi  = (int*)(ws + OFF_TOPI);
    int*   ptok  = (int*)(ws + OFF_PTOK);
    float* pgate = ws + OFF_PGATE;
    int*   tokp  = (int*)(ws + OFF_TOKP);
    int*   cnt   = (int*)(ws + OFF_CNT);
    float* psum  = ws + OFF_PSUM;
    int*   offs  = (int*)(ws + OFF_OFFS);
    int*   curs  = (int*)(ws + OFF_CURS);
    int*   seli  = (int*)(ws + OFF_SELI);
    int*   selc  = (int*)(ws + OFF_SELC);
    // MoE-phase aliases
    float* yb = ws + OFF_Y2;
    unsigned short* WpH = (unsigned short*)(ws + OFF_WPH);
    unsigned short* WpM = (unsigned short*)(ws + OFF_WPM);
    unsigned short* Xh  = (unsigned short*)(ws + OFF_XH);
    unsigned short* Xm  = (unsigned short*)(ws + OFF_XM);
    unsigned short* Hh  = (unsigned short*)(ws + OFF_HH);
    unsigned short* Hm  = (unsigned short*)(ws + OFF_HM);

    // zero the small counter block (cnt, psum, offs, curs)
    hipMemsetAsync(ws + OFF_CNT, 0, 256, stream);

    // --- norm1 ---
    rmsnorm_k<<<T, 256, 0, stream>>>(x, n1w, xn);
    // --- indexer projections (fp32 kernel: keep top-512 selection bit-stable) ---
    gemm_k<<<dim3(4, 16, 1), 256, 0, stream>>>(xn, Dm, wq_idx, 256, 0, qi, 256,
        nullptr, 0, nullptr, nullptr, nullptr, nullptr, 256, Dm, 0);
    gemm_k<<<dim3(1, 16, 1), 256, 0, stream>>>(xn, Dm, wk_idx, 64, 0, kib, 64,
        nullptr, 0, nullptr, nullptr, nullptr, nullptr, 64, Dm, 0);
    smalln_k<<<T / 4, 256, 0, stream>>>(xn, w_head, hwb, 4);
    // --- QKV: one fused multi-B launch (z selects wq/wk/wv; C offset z*T*Dm) ---
    mgemm_k<3><<<dim3(8, 16, 3), 256, 0, stream>>>(xn, Dm, wq, Dm, 0, wk, wvp, (ll)T * Dm,
        qb, Dm, nullptr, 0, nullptr, nullptr, nullptr, nullptr, Dm, Dm, 0);
    rope_k<<<4096, 256, 0, stream>>>(qb, kb);
    // --- indexer scores (full, unmasked -> output) + top-512 ---
    idx_k<<<dim3(32, 32, 1), 256, 0, stream>>>(qi, kib, hwb, idxs);
    topk_k<<<T, 256, 0, stream>>>(idxs, seli, selc);
    // --- sparse attention ---
    attn_k<<<T, 256, 0, stream>>>(qb, kb, vb, seli, selc, av);
    // --- wo + residual (NS=3: feeds router selection) ---
    mgemm_k<3><<<dim3(8, 16, 1), 256, 0, stream>>>(av, Dm, wo, Dm, 0, nullptr, nullptr, 0,
        x1, Dm, nullptr, 0, x, nullptr, nullptr, nullptr, Dm, Dm, 4);
    // --- norm2 + router ---
    rmsnorm_k<<<T, 256, 0, stream>>>(x1, n2w, x2n);
    router_k<<<T / 4, 256, 0, stream>>>(x2n, rw, rb, probs, gates, topi, cnt, psum);
    offs_k<<<1, 64, 0, stream>>>(cnt, offs);
    scatter_k<<<T / 256, 256, 0, stream>>>(topi, gates, offs, curs, ptok, pgate, tokp);
    // --- MoE: pre-split planes + 2-plane bf16 MFMA GEMMs ---
    split_k<<<T * Dm / 1024, 256, 0, stream>>>(x2n, Xh, Xm);
    for (int c = 0; c < DFF / MCH; c++) {
        // w1 slice [Dm][MCH] -> planes [e][MCH][Dm]
        tsplit_k<<<dim3(MCH / 64, Dm / 64, 8), 256, 0, stream>>>(
            w1 + c * MCH, DFF, (ll)Dm * DFF, WpH, WpM, (ll)MCH * Dm, Dm, MCH);
        // hmid planes = split(gelu(x2n[gather] @ w1c + b1))
        pgemm_k<<<dim3(MCH / 128, 16, 8), 256, 0, stream>>>(
            Xh, Xm, Dm, WpH, WpM, (ll)MCH * Dm, Dm,
            nullptr, 0, Hh, Hm, MCH, b1 + c * MCH, DFF, ptok, cnt, offs, MCH, Dm, 3);
        // w2 slice [MCH][Dm] -> planes [e][Dm][MCH]
        tsplit_k<<<dim3(Dm / 64, MCH / 64, 8), 256, 0, stream>>>(
            w2 + (ll)c * MCH * Dm, Dm, (ll)DFF * Dm, WpH, WpM, (ll)MCH * Dm, MCH, Dm);
        // y (+)= hmid @ w2c  (+ b2 on first chunk)
        pgemm_k<<<dim3(Dm / 128, 16, 8), 256, 0, stream>>>(
            Hh, Hm, MCH, WpH, WpM, (ll)MCH * Dm, MCH,
            yb, Dm, nullptr, nullptr, 0, b2, Dm, nullptr, cnt, offs, Dm, MCH, (c == 0) ? 1 : 8);
    }
    // --- combine + aux ---
    combine_k<<<T * Dm / 4 / 256, 256, 0, stream>>>(x1, yb, tokp, pgate, out);
    aux_k<<<1, 64, 0, stream>>>(cnt, psum, auxp);
}

// Round 4
// 2353.680 us; speedup vs baseline: 1.1914x; 1.1914x over previous
//
#include <hip/hip_runtime.h>

typedef long long ll;
typedef __bf16 bf16x8 __attribute__((ext_vector_type(8)));
typedef float f32x4 __attribute__((ext_vector_type(4)));
typedef unsigned short ushort_t;

#define T 2048
#define Dm 1024
#define DFF 4096
#define SPK 512
#define MCH 1024     // DFF chunk for MoE (4 chunks)

// ---------------- workspace offsets (in floats) ----------------
static const ll OFF_XN    = 0;          // 2048*1024 fp32 (dead after QKV/indexer)
static const ll OFF_Q     = 2097152;    // 2048*1024 (dead after attn)
static const ll OFF_K     = 4194304;    // 2048*1024 (dead after attn)
static const ll OFF_V     = 6291456;    // 2048*1024 (dead after attn)
static const ll OFF_AV    = 8388608;    // 2048*1024 (dead after wo)
static const ll OFF_X1    = 10485760;   // 2048*1024 (live to end; free until wo)
static const ll OFF_X2N   = 12582912;   // 2048*1024 (x2n dead after split)
static const ll OFF_QI    = 14680064;   // 2048*256
static const ll OFF_KI    = 15204352;   // 2048*64
static const ll OFF_HW    = 15335424;   // 2048*4
static const ll OFF_PROBS = 15343616;   // 2048*8
static const ll OFF_GATES = 15360000;   // 2048*2
static const ll OFF_TOPI  = 15364096;   // 2048*2 int
static const ll OFF_PTOK  = 15368192;   // 5120 int
static const ll OFF_PGATE = 15373312;   // 5120
static const ll OFF_TOKP  = 15378432;   // 2048*2 int
static const ll OFF_CNT   = 15382528;   // 8 int   -- memset-0 region
static const ll OFF_PSUM  = 15382536;   // 8 float
static const ll OFF_OFFS  = 15382544;   // 9 int
static const ll OFF_CURS  = 15382560;   // 8 int
static const ll OFF_SELI  = 15382592;   // 2048*512 int
static const ll OFF_SELC  = 16431168;   // 2048 int
// total ws = 16433216 floats = ~62.7 MiB (unchanged)
//
// Plane aliases (each plane of 2048x1024 bf16 = 1M floats):
//  P1 = xn planes (live: rmsnorm1 .. QKV):   H @X1, M @X1+1M, L @X2N
//  P2 = av planes (live: attn .. wo):        H @XN, M @XN+1M, L @X2N
//  Xp = x2n planes (live: split .. MoE g1):  H @Q,  M @Q+1M
//  Hp = hmid planes (per chunk, 4096x1024):  H @AV(2M), M @X2N(2M)
//  y  = 4096x1024 fp32 @K..V (4M floats)
static const ll OFF_P1H = OFF_X1;
static const ll OFF_P1M = OFF_X1 + 1048576;
static const ll OFF_P1L = OFF_X2N;
static const ll OFF_P2H = OFF_XN;
static const ll OFF_P2M = OFF_XN + 1048576;
static const ll OFF_P2L = OFF_X2N;
static const ll OFF_XPH = OFF_Q;
static const ll OFF_XPM = OFF_Q + 1048576;
static const ll OFF_HPH = OFF_AV;
static const ll OFF_HPM = OFF_X2N;
static const ll OFF_Y2  = OFF_K;

// ---------------- RMSNorm ----------------
__global__ __launch_bounds__(256) void rmsnorm_k(const float* __restrict__ x,
                                                 const float* __restrict__ w,
                                                 float* __restrict__ o) {
    int t = blockIdx.x, tid = threadIdx.x;
    __shared__ float red[4];
    float4 xv = ((const float4*)(x + (ll)t * Dm))[tid];
    float ss = xv.x * xv.x + xv.y * xv.y + xv.z * xv.z + xv.w * xv.w;
#pragma unroll
    for (int off = 32; off >= 1; off >>= 1) ss += __shfl_xor(ss, off);
    int lane = tid & 63, wv = tid >> 6;
    if (lane == 0) red[wv] = ss;
    __syncthreads();
    float tot = red[0] + red[1] + red[2] + red[3];
    float sc = 1.0f / sqrtf(tot * (1.0f / 1024.0f) + 1e-6f);
    float4 wv4 = ((const float4*)w)[tid];
    float4 ov;
    ov.x = xv.x * sc * wv4.x; ov.y = xv.y * sc * wv4.y;
    ov.z = xv.z * sc * wv4.z; ov.w = xv.w * sc * wv4.w;
    ((float4*)(o + (ll)t * Dm))[tid] = ov;
}

// ---------------- generic tiled fp32 GEMM (indexer path: bit-stable) ----------------
__global__ __launch_bounds__(256) void gemm_k(
    const float* __restrict__ A, int lda,
    const float* __restrict__ B, int ldb, ll ebB,
    float* __restrict__ C, int ldc,
    const float* __restrict__ bias, int ebBias,
    const float* __restrict__ resid,
    const int* __restrict__ gather,
    const int* __restrict__ gcnt, const int* __restrict__ goff,
    int N, int K, int flags) {
    int e = blockIdx.z;
    int m0, mvalid;
    if (gcnt) {
        int cnt = gcnt[e];
        mvalid = cnt - blockIdx.y * 128;
        if (mvalid <= 0) return;
        if (mvalid > 128) mvalid = 128;
        m0 = goff[e] + blockIdx.y * 128;
    } else {
        m0 = blockIdx.y * 128; mvalid = 128;
    }
    int n0 = blockIdx.x * 64;
    const float* Bp = B + (ll)e * ebB;
    __shared__ float As[8][132];
    __shared__ float Bs[8][64];
    int tid = threadIdx.x;
    int tx = tid & 15, ty = tid >> 4;
    int arow = tid >> 1, ak = (tid & 1) * 4;
    int brow = tid >> 4, bn = (tid & 15) * 4;
    ll aRow;
    int asrc = (arow < mvalid) ? arow : 0;
    if (gather) aRow = gather[m0 + asrc]; else aRow = m0 + asrc;
    const float* Aptr = A + aRow * (ll)lda + ak;
    bool bin = (tid < 128) && ((n0 + bn) < N);
    const float* Bptr0 = Bp + n0 + bn;
    float acc[8][4];
#pragma unroll
    for (int r = 0; r < 8; r++)
#pragma unroll
        for (int c = 0; c < 4; c++) acc[r][c] = 0.0f;

    for (int k0 = 0; k0 < K; k0 += 8) {
        float4 a4 = *(const float4*)(Aptr + k0);
        float4 b4 = make_float4(0.f, 0.f, 0.f, 0.f);
        if (bin) b4 = *(const float4*)(Bptr0 + (ll)(k0 + brow) * ldb);
        As[ak + 0][arow] = a4.x; As[ak + 1][arow] = a4.y;
        As[ak + 2][arow] = a4.z; As[ak + 3][arow] = a4.w;
        if (tid < 128) *(float4*)&Bs[brow][bn] = b4;
        __syncthreads();
#pragma unroll
        for (int kk = 0; kk < 8; kk++) {
            float4 a0 = *(const float4*)&As[kk][ty * 8];
            float4 a1 = *(const float4*)&As[kk][ty * 8 + 4];
            float4 b0 = *(const float4*)&Bs[kk][tx * 4];
            float aa[8] = {a0.x, a0.y, a0.z, a0.w, a1.x, a1.y, a1.z, a1.w};
            float bb[4] = {b0.x, b0.y, b0.z, b0.w};
#pragma unroll
            for (int r = 0; r < 8; r++)
#pragma unroll
                for (int c = 0; c < 4; c++)
                    acc[r][c] = fmaf(aa[r], bb[c], acc[r][c]);
        }
        __syncthreads();
    }
#pragma unroll
    for (int r = 0; r < 8; r++) {
        int i = ty * 8 + r;
        if (i >= mvalid) continue;
        ll gm = (ll)(m0 + i);
#pragma unroll
        for (int c = 0; c < 4; c++) {
            int j = n0 + tx * 4 + c;
            if (j >= N) continue;
            float vv = acc[r][c];
            if (flags & 1) vv += bias[(ll)e * ebBias + j];
            if (flags & 2) {
                float g = vv;
                vv = 0.5f * g * (1.0f + tanhf(0.7978845608028654f * (g + 0.044715f * g * g * g)));
            }
            if (flags & 4) vv += resid[gm * ldc + j];
            if (flags & 8) vv += C[gm * ldc + j];
            C[gm * ldc + j] = vv;
        }
    }
}

// ---------------- split helpers ----------------
__device__ __forceinline__ void splitf(float x, ushort_t& h, ushort_t& m) {
    unsigned u = __float_as_uint(x);
    unsigned hv = u & 0xFFFF0000u;
    float r = x - __uint_as_float(hv);
    h = (ushort_t)(hv >> 16);
    m = (ushort_t)(__float_as_uint(r) >> 16);
}

__device__ __forceinline__ void splitf3(float x, ushort_t& h, ushort_t& m, ushort_t& l) {
    unsigned u = __float_as_uint(x);
    unsigned hv = u & 0xFFFF0000u;
    float r = x - __uint_as_float(hv);
    unsigned mv = __float_as_uint(r) & 0xFFFF0000u;
    float s = r - __uint_as_float(mv);
    h = (ushort_t)(hv >> 16);
    m = (ushort_t)(mv >> 16);
    l = (ushort_t)(__float_as_uint(s) >> 16);
}

__device__ __forceinline__ void split2(float x0, float x1,
                                       unsigned& h, unsigned& m, unsigned& l) {
    unsigned u0 = __float_as_uint(x0), u1 = __float_as_uint(x1);
    unsigned h0 = u0 & 0xFFFF0000u, h1 = u1 & 0xFFFF0000u;
    float r0 = x0 - __uint_as_float(h0);
    float r1 = x1 - __uint_as_float(h1);
    unsigned v0 = __float_as_uint(r0), v1 = __float_as_uint(r1);
    unsigned q0 = v0 & 0xFFFF0000u, q1 = v1 & 0xFFFF0000u;
    float s0 = r0 - __uint_as_float(q0);
    float s1 = r1 - __uint_as_float(q1);
    h = (h0 >> 16) | h1;
    m = (q0 >> 16) | q1;
    l = (__float_as_uint(s0) >> 16) | (__float_as_uint(s1) & 0xFFFF0000u);
}

__device__ __forceinline__ void st16(ushort_t* dst, const unsigned* p) {
    uint4 u; u.x = p[0]; u.y = p[1]; u.z = p[2]; u.w = p[3];
    *(uint4*)dst = u;
}

// elementwise fp32 -> NP bf16 truncation planes
template<int NP>
__global__ __launch_bounds__(256) void splitp_k(const float* __restrict__ src,
                                                ushort_t* __restrict__ dh,
                                                ushort_t* __restrict__ dm,
                                                ushort_t* __restrict__ dl) {
    ll i = ((ll)blockIdx.x * 256 + threadIdx.x) * 4;
    float4 v = *(const float4*)(src + i);
    ushort4 h4, m4, l4;
    if constexpr (NP == 3) {
        splitf3(v.x, h4.x, m4.x, l4.x); splitf3(v.y, h4.y, m4.y, l4.y);
        splitf3(v.z, h4.z, m4.z, l4.z); splitf3(v.w, h4.w, m4.w, l4.w);
        *(ushort4*)&dl[i] = l4;
    } else {
        splitf(v.x, h4.x, m4.x); splitf(v.y, h4.y, m4.y);
        splitf(v.z, h4.z, m4.z); splitf(v.w, h4.w, m4.w);
    }
    *(ushort4*)&dh[i] = h4;
    *(ushort4*)&dm[i] = m4;
}

// ---------------- pgemm3: NS=3 MFMA GEMM, pre-split A planes ----------------
// Bit-identical products/order to the previous NS=3 mgemm (selection-safe).
// Dense M=2048 only. Multi-B via blockIdx.z (B/B2/B3, C += z*ebC). flags: 4=+resid.
__global__ __launch_bounds__(256) void pgemm3_k(
    const ushort_t* __restrict__ Ah, const ushort_t* __restrict__ Am,
    const ushort_t* __restrict__ Al, int lda,
    const float* __restrict__ B, int ldb,
    const float* __restrict__ B2, const float* __restrict__ B3, ll ebC,
    float* __restrict__ C, int ldc,
    const float* __restrict__ resid,
    int N, int K, int flags) {
    int e = blockIdx.z;
    const float* Bp = (B2 == nullptr || e == 0) ? B : (e == 1 ? B2 : B3);
    float* Cp = C + (ll)e * ebC;
    int m0 = blockIdx.y * 128, n0 = blockIdx.x * 128;

    // stride 40 ushorts = 80B rows: 16B-aligned + only 2-way frag-read conflicts (free)
    __shared__ __align__(16) ushort_t AsH[128][40], AsM[128][40], AsL[128][40];
    __shared__ __align__(16) ushort_t BsH[128][40], BsM[128][40], BsL[128][40];

    int tid = threadIdx.x;
    int arow = tid >> 1, ak = (tid & 1) * 16;
    const ushort_t* pAH = Ah + (ll)(m0 + arow) * lda + ak;
    const ushort_t* pAM = Am + (ll)(m0 + arow) * lda + ak;
    const ushort_t* pAL = Al + (ll)(m0 + arow) * lda + ak;
    int bn = tid & 127, bk = (tid >> 7) * 16;
    const float* Bpp = Bp + (ll)bk * ldb + n0 + bn;

    int lane = tid & 63, wid = tid >> 6;
    int wr = (wid >> 1) * 64, wc = (wid & 1) * 64;
    int fr = lane & 15, fk = (lane >> 4) * 8;

    f32x4 acc[4][4];
    f32x4 zero4 = {0.0f, 0.0f, 0.0f, 0.0f};
#pragma unroll
    for (int i = 0; i < 4; i++)
#pragma unroll
        for (int j = 0; j < 4; j++) acc[i][j] = zero4;

    for (int k0 = 0; k0 < K; k0 += 32) {
        uint4 aH0 = *(const uint4*)(pAH + k0), aH1 = *(const uint4*)(pAH + k0 + 8);
        uint4 aM0 = *(const uint4*)(pAM + k0), aM1 = *(const uint4*)(pAM + k0 + 8);
        uint4 aL0 = *(const uint4*)(pAL + k0), aL1 = *(const uint4*)(pAL + k0 + 8);
        float bbuf[16];
        const float* bp = Bpp + (ll)k0 * ldb;
#pragma unroll
        for (int i = 0; i < 16; i++) bbuf[i] = bp[(ll)i * ldb];

        __syncthreads();   // prev iteration's frag reads complete

        *(uint4*)&AsH[arow][ak] = aH0; *(uint4*)&AsH[arow][ak + 8] = aH1;
        *(uint4*)&AsM[arow][ak] = aM0; *(uint4*)&AsM[arow][ak + 8] = aM1;
        *(uint4*)&AsL[arow][ak] = aL0; *(uint4*)&AsL[arow][ak + 8] = aL1;

        unsigned ph[8], pm[8], pl[8];
        split2(bbuf[0],  bbuf[1],  ph[0], pm[0], pl[0]);
        split2(bbuf[2],  bbuf[3],  ph[1], pm[1], pl[1]);
        split2(bbuf[4],  bbuf[5],  ph[2], pm[2], pl[2]);
        split2(bbuf[6],  bbuf[7],  ph[3], pm[3], pl[3]);
        split2(bbuf[8],  bbuf[9],  ph[4], pm[4], pl[4]);
        split2(bbuf[10], bbuf[11], ph[5], pm[5], pl[5]);
        split2(bbuf[12], bbuf[13], ph[6], pm[6], pl[6]);
        split2(bbuf[14], bbuf[15], ph[7], pm[7], pl[7]);
        st16(&BsH[bn][bk], ph);  st16(&BsH[bn][bk + 8], ph + 4);
        st16(&BsM[bn][bk], pm); st16(&BsM[bn][bk + 8], pm + 4);
        st16(&BsL[bn][bk], pl);  st16(&BsL[bn][bk + 8], pl + 4);

        __syncthreads();

        bf16x8 Afh[4], Afm[4], Afl[4];
#pragma unroll
        for (int mi = 0; mi < 4; mi++) {
            int rr = wr + mi * 16 + fr;
            Afh[mi] = *(const bf16x8*)&AsH[rr][fk];
            Afm[mi] = *(const bf16x8*)&AsM[rr][fk];
            Afl[mi] = *(const bf16x8*)&AsL[rr][fk];
        }
#pragma unroll
        for (int ni = 0; ni < 4; ni++) {
            int rc = wc + ni * 16 + fr;
            bf16x8 bh = *(const bf16x8*)&BsH[rc][fk];
            bf16x8 bm = *(const bf16x8*)&BsM[rc][fk];
            bf16x8 bl = *(const bf16x8*)&BsL[rc][fk];
#pragma unroll
            for (int mi = 0; mi < 4; mi++) {
                f32x4 c = acc[mi][ni];
                c = __builtin_amdgcn_mfma_f32_16x16x32_bf16(Afh[mi], bh, c, 0, 0, 0);
                c = __builtin_amdgcn_mfma_f32_16x16x32_bf16(Afh[mi], bm, c, 0, 0, 0);
                c = __builtin_amdgcn_mfma_f32_16x16x32_bf16(Afm[mi], bh, c, 0, 0, 0);
                c = __builtin_amdgcn_mfma_f32_16x16x32_bf16(Afh[mi], bl, c, 0, 0, 0);
                c = __builtin_amdgcn_mfma_f32_16x16x32_bf16(Afm[mi], bm, c, 0, 0, 0);
                c = __builtin_amdgcn_mfma_f32_16x16x32_bf16(Afl[mi], bh, c, 0, 0, 0);
                acc[mi][ni] = c;
            }
        }
    }

    int frow = (lane >> 4) * 4;
#pragma unroll
    for (int ni = 0; ni < 4; ni++) {
        int j = n0 + wc + ni * 16 + fr;
#pragma unroll
        for (int mi = 0; mi < 4; mi++) {
            int ib = wr + mi * 16 + frow;
#pragma unroll
            for (int r = 0; r < 4; r++) {
                int i = ib + r;
                ll gm = (ll)(m0 + i);
                float vv = acc[mi][ni][r] + 0.0f;
                if (flags & 4) vv += resid[gm * ldc + j];
                Cp[gm * ldc + j] = vv;
            }
        }
    }
}

// ---------------- pgemm2: MoE grouped GEMM, A 2-plane + B single rne-bf16 ----------------
// C = (Ah+Am)·bf16(B) via 2 MFMA products. Purely-additive path (no downstream selection).
// If Ch!=null: epilogue writes bf16 hi/m planes (trunc split) of bias/gelu'd result.
// flags: 1=+bias  2=gelu  8=accumulate into C
__global__ __launch_bounds__(256) void pgemm2_k(
    const ushort_t* __restrict__ Ah, const ushort_t* __restrict__ Am, int lda,
    const float* __restrict__ B, int ldb, ll ebB,
    float* __restrict__ C, int ldc,
    ushort_t* __restrict__ Ch, ushort_t* __restrict__ Cm, int ldch,
    const float* __restrict__ bias, int ebBias,
    const int* __restrict__ gather,
    const int* __restrict__ gcnt, const int* __restrict__ goff,
    int N, int K, int flags) {
    int e = blockIdx.z;
    int cnt = gcnt[e];
    int mvalid = cnt - blockIdx.y * 128;
    if (mvalid <= 0) return;
    if (mvalid > 128) mvalid = 128;
    int m0 = goff[e] + blockIdx.y * 128;
    int n0 = blockIdx.x * 128;
    const float* Bp = B + (ll)e * ebB;

    __shared__ __align__(16) ushort_t AsH[128][40], AsM[128][40];
    __shared__ __align__(16) ushort_t Bs[128][40];

    int tid = threadIdx.x;
    int arow = tid >> 1, ak = (tid & 1) * 16;
    int asrc = (arow < mvalid) ? arow : 0;
    ll aRowG = gather ? (ll)gather[m0 + asrc] : (ll)(m0 + asrc);
    const ushort_t* pAH = Ah + aRowG * (ll)lda + ak;
    const ushort_t* pAM = Am + aRowG * (ll)lda + ak;
    int bn = tid & 127, bk = (tid >> 7) * 16;
    const float* Bpp = Bp + (ll)bk * ldb + n0 + bn;

    int lane = tid & 63, wid = tid >> 6;
    int wr = (wid >> 1) * 64, wc = (wid & 1) * 64;
    int fr = lane & 15, fk = (lane >> 4) * 8;

    f32x4 acc[4][4];
    f32x4 zero4 = {0.0f, 0.0f, 0.0f, 0.0f};
#pragma unroll
    for (int i = 0; i < 4; i++)
#pragma unroll
        for (int j = 0; j < 4; j++) acc[i][j] = zero4;

    for (int k0 = 0; k0 < K; k0 += 32) {
        uint4 aH0 = *(const uint4*)(pAH + k0), aH1 = *(const uint4*)(pAH + k0 + 8);
        uint4 aM0 = *(const uint4*)(pAM + k0), aM1 = *(const uint4*)(pAM + k0 + 8);
        float bbuf[16];
        const float* bp = Bpp + (ll)k0 * ldb;
#pragma unroll
        for (int i = 0; i < 16; i++) bbuf[i] = bp[(ll)i * ldb];

        __syncthreads();

        *(uint4*)&AsH[arow][ak] = aH0; *(uint4*)&AsH[arow][ak + 8] = aH1;
        *(uint4*)&AsM[arow][ak] = aM0; *(uint4*)&AsM[arow][ak + 8] = aM1;
        unsigned bbw[8];
#pragma unroll
        for (int j = 0; j < 8; j++) {
            __bf16 lo = (__bf16)bbuf[2 * j], hi = (__bf16)bbuf[2 * j + 1];
            bbw[j] = (unsigned)__builtin_bit_cast(ushort_t, lo) |
                     ((unsigned)__builtin_bit_cast(ushort_t, hi) << 16);
        }
        st16(&Bs[bn][bk], bbw); st16(&Bs[bn][bk + 8], bbw + 4);

        __syncthreads();

        bf16x8 Afh[4], Afm[4];
#pragma unroll
        for (int mi = 0; mi < 4; mi++) {
            int rr = wr + mi * 16 + fr;
            Afh[mi] = *(const bf16x8*)&AsH[rr][fk];
            Afm[mi] = *(const bf16x8*)&AsM[rr][fk];
        }
#pragma unroll
        for (int ni = 0; ni < 4; ni++) {
            int rc = wc + ni * 16 + fr;
            bf16x8 bh = *(const bf16x8*)&Bs[rc][fk];
#pragma unroll
            for (int mi = 0; mi < 4; mi++) {
                f32x4 c = acc[mi][ni];
                c = __builtin_amdgcn_mfma_f32_16x16x32_bf16(Afh[mi], bh, c, 0, 0, 0);
                c = __builtin_amdgcn_mfma_f32_16x16x32_bf16(Afm[mi], bh, c, 0, 0, 0);
                acc[mi][ni] = c;
            }
        }
    }

    int frow = (lane >> 4) * 4;
#pragma unroll
    for (int ni = 0; ni < 4; ni++) {
        int j = n0 + wc + ni * 16 + fr;
        float bv = (flags & 1) ? bias[(ll)e * ebBias + j] : 0.0f;
#pragma unroll
        for (int mi = 0; mi < 4; mi++) {
            int ib = wr + mi * 16 + frow;
#pragma unroll
            for (int r = 0; r < 4; r++) {
                int i = ib + r;
                if (i >= mvalid) continue;
                ll gm = (ll)(m0 + i);
                float vv = acc[mi][ni][r] + bv;
                if (flags & 2) {
                    float g = vv;
                    vv = 0.5f * g * (1.0f + tanhf(0.7978845608028654f * (g + 0.044715f * g * g * g)));
                }
                if (Ch) {
                    ushort_t hh, mm;
                    splitf(vv, hh, mm);
                    Ch[gm * ldch + j] = hh;
                    Cm[gm * ldch + j] = mm;
                } else {
                    if (flags & 8) vv += C[gm * ldc + j];
                    C[gm * ldc + j] = vv;
                }
            }
        }
    }
}

// ---------------- small-N projection (wave per token) ----------------
__global__ __launch_bounds__(256) void smalln_k(const float* __restrict__ A,
                                                const float* __restrict__ W,
                                                float* __restrict__ Co, int N) {
    int wv = (blockIdx.x * 256 + threadIdx.x) >> 6;
    int lane = threadIdx.x & 63;
    if (wv >= T) return;
    const float* a = A + (ll)wv * Dm;
    float xs[16];
#pragma unroll
    for (int i = 0; i < 16; i++) xs[i] = a[lane + 64 * i];
    for (int n = 0; n < N; n++) {
        float s = 0.0f;
#pragma unroll
        for (int i = 0; i < 16; i++) s = fmaf(xs[i], W[(ll)(lane + 64 * i) * N + n], s);
#pragma unroll
        for (int off = 32; off >= 1; off >>= 1) s += __shfl_xor(s, off);
        if (lane == 0) Co[(ll)wv * N + n] = s;
    }
}

// ---------------- RoPE (q and k in place) ----------------
__global__ __launch_bounds__(256) void rope_k(float* __restrict__ q, float* __restrict__ k) {
    int i = blockIdx.x * 256 + threadIdx.x;   // T*16*32
    int d = i & 31; int h = (i >> 5) & 15; int t = i >> 9;
    float inv = powf(10000.0f, -(float)(2 * d) * (1.0f / 64.0f));
    float ang = (float)t * inv;
    float cs = cosf(ang), sn = sinf(ang);
    ll base = (ll)t * Dm + h * 64 + d;
    float a = q[base], b = q[base + 32];
    q[base] = a * cs - b * sn; q[base + 32] = b * cs + a * sn;
    a = k[base]; b = k[base + 32];
    k[base] = a * cs - b * sn; k[base + 32] = b * cs + a * sn;
}

// ---------------- lightning indexer scores (full TxT, unmasked) ----------------
__global__ __launch_bounds__(256) void idx_k(const float* __restrict__ qi,
                                             const float* __restrict__ ki,
                                             const float* __restrict__ hww,
                                             float* __restrict__ out) {
    __shared__ float Aq[64][65];
    __shared__ float Bk[64][65];
    __shared__ float hs[64][4];
    int t0 = blockIdx.y * 64, s0 = blockIdx.x * 64;
    int tid = threadIdx.x;
    int tx = tid & 15, ty = tid >> 4;
    int ty4 = ty * 4, tx4 = tx * 4;
    if (tid < 64) {
#pragma unroll
        for (int e = 0; e < 4; e++) hs[tid][e] = hww[(ll)(t0 + tid) * 4 + e];
    }
#pragma unroll
    for (int it = 0; it < 4; it++) {
        int f4 = tid + it * 256;
        int row = f4 >> 4, c4 = (f4 & 15) * 4;
        float4 kv = *(const float4*)(ki + (ll)(s0 + row) * 64 + c4);
        Bk[row][c4] = kv.x; Bk[row][c4 + 1] = kv.y; Bk[row][c4 + 2] = kv.z; Bk[row][c4 + 3] = kv.w;
    }
    float acc[4][4];
#pragma unroll
    for (int r = 0; r < 4; r++)
#pragma unroll
        for (int c = 0; c < 4; c++) acc[r][c] = 0.0f;

    for (int h = 0; h < 4; h++) {
        __syncthreads();
#pragma unroll
        for (int it = 0; it < 4; it++) {
            int f4 = tid + it * 256;
            int row = f4 >> 4, c4 = (f4 & 15) * 4;
            float4 qv = *(const float4*)(qi + (ll)(t0 + row) * 256 + h * 64 + c4);
            Aq[row][c4] = qv.x; Aq[row][c4 + 1] = qv.y; Aq[row][c4 + 2] = qv.z; Aq[row][c4 + 3] = qv.w;
        }
        __syncthreads();
        float dh[4][4];
#pragma unroll
        for (int r = 0; r < 4; r++)
#pragma unroll
            for (int c = 0; c < 4; c++) dh[r][c] = 0.0f;
#pragma unroll 8
        for (int d = 0; d < 64; d++) {
            float a0 = Aq[ty4 + 0][d], a1 = Aq[ty4 + 1][d], a2 = Aq[ty4 + 2][d], a3 = Aq[ty4 + 3][d];
            float b0 = Bk[tx4 + 0][d], b1 = Bk[tx4 + 1][d], b2 = Bk[tx4 + 2][d], b3 = Bk[tx4 + 3][d];
            dh[0][0] = fmaf(a0, b0, dh[0][0]); dh[0][1] = fmaf(a0, b1, dh[0][1]);
            dh[0][2] = fmaf(a0, b2, dh[0][2]); dh[0][3] = fmaf(a0, b3, dh[0][3]);
            dh[1][0] = fmaf(a1, b0, dh[1][0]); dh[1][1] = fmaf(a1, b1, dh[1][1]);
            dh[1][2] = fmaf(a1, b2, dh[1][2]); dh[1][3] = fmaf(a1, b3, dh[1][3]);
            dh[2][0] = fmaf(a2, b0, dh[2][0]); dh[2][1] = fmaf(a2, b1, dh[2][1]);
            dh[2][2] = fmaf(a2, b2, dh[2][2]); dh[2][3] = fmaf(a2, b3, dh[2][3]);
            dh[3][0] = fmaf(a3, b0, dh[3][0]); dh[3][1] = fmaf(a3, b1, dh[3][1]);
            dh[3][2] = fmaf(a3, b2, dh[3][2]); dh[3][3] = fmaf(a3, b3, dh[3][3]);
        }
#pragma unroll
        for (int r = 0; r < 4; r++) {
            float hv = hs[ty4 + r][h];
#pragma unroll
            for (int c = 0; c < 4; c++)
                acc[r][c] = fmaf(hv, fmaxf(dh[r][c], 0.0f), acc[r][c]);
        }
    }
#pragma unroll
    for (int r = 0; r < 4; r++)
#pragma unroll
        for (int c = 0; c < 4; c++)
            out[(ll)(t0 + ty4 + r) * T + s0 + tx4 + c] = acc[r][c] * 0.125f;
}

// ---------------- exact top-512 per row: 64-bit radix select ----------------
__global__ __launch_bounds__(256) void topk_k(const float* __restrict__ idx,
                                              int* __restrict__ seli,
                                              int* __restrict__ selc) {
    int t = blockIdx.x, tid = threadIdx.x;
    const float* row = idx + (ll)t * T;
    if (t < SPK) {
        for (int s = tid; s <= t; s += 256) seli[(ll)t * SPK + s] = s;
        if (tid == 0) selc[t] = t + 1;
        return;
    }
    __shared__ unsigned int hist[256];
    __shared__ unsigned long long sh_prefix;
    __shared__ int sh_k, sh_cur;
    if (tid == 0) { sh_prefix = 0ULL; sh_k = SPK; sh_cur = 0; }
    for (int p = 7; p >= 0; p--) {
        hist[tid] = 0u;
        __syncthreads();
        unsigned long long prefix = sh_prefix;
        unsigned long long maskhi = (p == 7) ? 0ULL : ((~0ULL) << ((p + 1) * 8));
        for (int s = tid; s <= t; s += 256) {
            unsigned int u = __float_as_uint(row[s]);
            u = (u & 0x80000000u) ? ~u : (u | 0x80000000u);
            unsigned long long key = ((unsigned long long)u << 32) | (unsigned int)(0xFFFFFFFFu - (unsigned int)s);
            if ((key & maskhi) == prefix)
                atomicAdd(&hist[(unsigned int)(key >> (p * 8)) & 0xFFu], 1u);
        }
        __syncthreads();
        if (tid == 0) {
            int rem = sh_k, b;
            for (b = 255; b > 0; b--) {
                int hc = (int)hist[b];
                if (hc >= rem) break;
                rem -= hc;
            }
            sh_prefix = prefix | ((unsigned long long)(unsigned int)b << (p * 8));
            sh_k = rem;
        }
        __syncthreads();
    }
    unsigned long long tau = sh_prefix;
    for (int s = tid; s <= t; s += 256) {
        unsigned int u = __float_as_uint(row[s]);
        u = (u & 0x80000000u) ? ~u : (u | 0x80000000u);
        unsigned long long key = ((unsigned long long)u << 32) | (unsigned int)(0xFFFFFFFFu - (unsigned int)s);
        if (key >= tau) {
            int pos = atomicAdd(&sh_cur, 1);
            seli[(ll)t * SPK + pos] = s;
        }
    }
    __syncthreads();
    if (tid == 0) selc[t] = sh_cur;
}

// ---------------- sparse attention: block per query token, all 16 heads ----------------
__global__ __launch_bounds__(256) void attn_k(const float* __restrict__ q,
                                              const float* __restrict__ k,
                                              const float* __restrict__ v,
                                              const int* __restrict__ seli,
                                              const int* __restrict__ selc,
                                              float* __restrict__ av) {
    int t = blockIdx.x, tid = threadIdx.x;
    __shared__ float qs[1024];
    __shared__ float sc[16 * 513];
    __shared__ int ssel[512];
    int n = selc[t];
    ((float4*)qs)[tid] = ((const float4*)(q + (ll)t * Dm))[tid];
    for (int j = tid; j < n; j += 256) ssel[j] = seli[(ll)t * SPK + j];
    __syncthreads();
    int lane = tid & 63, w = tid >> 6;
    int h = lane >> 2, part = lane & 3;
    const float4* qp = (const float4*)(qs + lane * 16);
    float4 q0 = qp[0], q1 = qp[1], q2 = qp[2], q3 = qp[3];
    for (int j = w; j < n; j += 4) {
        int s = ssel[j];
        const float4* kp = (const float4*)(k + (ll)s * Dm + lane * 16);
        float4 k0 = kp[0], k1 = kp[1], k2 = kp[2], k3 = kp[3];
        float d;
        d  = q0.x * k0.x + q0.y * k0.y + q0.z * k0.z + q0.w * k0.w;
        d += q1.x * k1.x + q1.y * k1.y + q1.z * k1.z + q1.w * k1.w;
        d += q2.x * k2.x + q2.y * k2.y + q2.z * k2.z + q2.w * k2.w;
        d += q3.x * k3.x + q3.y * k3.y + q3.z * k3.z + q3.w * k3.w;
        d += __shfl_xor(d, 1);
        d += __shfl_xor(d, 2);
        if (part == 0) sc[h * 513 + j] = d * 0.125f;
    }
    __syncthreads();
    for (int hh = w * 4; hh < w * 4 + 4; hh++) {
        float m = -3.0e38f;
        for (int j = lane; j < n; j += 64) m = fmaxf(m, sc[hh * 513 + j]);
#pragma unroll
        for (int off = 32; off >= 1; off >>= 1) m = fmaxf(m, __shfl_xor(m, off));
        float ssum = 0.0f;
        for (int j = lane; j < n; j += 64) {
            float p = expf(sc[hh * 513 + j] - m);
            sc[hh * 513 + j] = p; ssum += p;
        }
#pragma unroll
        for (int off = 32; off >= 1; off >>= 1) ssum += __shfl_xor(ssum, off);
        float inv = 1.0f / ssum;
        for (int j = lane; j < n; j += 64) sc[hh * 513 + j] *= inv;
    }
    __syncthreads();
    int base = tid * 4, oh = tid >> 4;
    float ax = 0, ay = 0, az = 0, aw = 0;
    for (int j = 0; j < n; j++) {
        float p = sc[oh * 513 + j];
        float4 vv = *(const float4*)(v + (ll)ssel[j] * Dm + base);
        ax = fmaf(p, vv.x, ax); ay = fmaf(p, vv.y, ay);
        az = fmaf(p, vv.z, az); aw = fmaf(p, vv.w, aw);
    }
    float4 o4; o4.x = ax; o4.y = ay; o4.z = az; o4.w = aw;
    *(float4*)(av + (ll)t * Dm + base) = o4;
}

// ---------------- router: softmax + top2 + aux accumulators ----------------
__global__ __launch_bounds__(256) void router_k(const float* __restrict__ x2n,
                                                const float* __restrict__ rw,
                                                const float* __restrict__ rb,
                                                float* __restrict__ probs,
                                                float* __restrict__ gates,
                                                int* __restrict__ topi,
                                                int* __restrict__ cnt,
                                                float* __restrict__ psum) {
    int wv = (blockIdx.x * 256 + threadIdx.x) >> 6;
    int lane = threadIdx.x & 63;
    if (wv >= T) return;
    const float* a = x2n + (ll)wv * Dm;
    float l[8] = {0, 0, 0, 0, 0, 0, 0, 0};
    for (int i = 0; i < 16; i++) {
        int kk = lane + 64 * i;
        float xk = a[kk];
        const float* rp = rw + (ll)kk * 8;
#pragma unroll
        for (int e = 0; e < 8; e++) l[e] = fmaf(xk, rp[e], l[e]);
    }
#pragma unroll
    for (int e = 0; e < 8; e++) {
#pragma unroll
        for (int off = 32; off >= 1; off >>= 1) l[e] += __shfl_xor(l[e], off);
    }
    if (lane == 0) {
        float m = -3.0e38f;
#pragma unroll
        for (int e = 0; e < 8; e++) { l[e] += rb[e]; m = fmaxf(m, l[e]); }
        float p[8], s = 0.0f;
#pragma unroll
        for (int e = 0; e < 8; e++) { p[e] = expf(l[e] - m); s += p[e]; }
        float invs = 1.0f / s;
#pragma unroll
        for (int e = 0; e < 8; e++) {
            p[e] *= invs;
            probs[(ll)wv * 8 + e] = p[e];
            atomicAdd(&psum[e], p[e]);
        }
        int i1 = 0; float v1 = p[0];
#pragma unroll
        for (int e = 1; e < 8; e++) if (p[e] > v1) { v1 = p[e]; i1 = e; }
        int i2 = -1; float v2 = -1.0f;
#pragma unroll
        for (int e = 0; e < 8; e++) if (e != i1 && p[e] > v2) { v2 = p[e]; i2 = e; }
        float g = 1.0f / (v1 + v2);
        gates[wv * 2] = v1 * g; gates[wv * 2 + 1] = v2 * g;
        topi[wv * 2] = i1; topi[wv * 2 + 1] = i2;
        atomicAdd(&cnt[i1], 1); atomicAdd(&cnt[i2], 1);
    }
}

__global__ void offs_k(const int* __restrict__ cnt, int* __restrict__ offs) {
    if (threadIdx.x == 0 && blockIdx.x == 0) {
        int o = 0;
        for (int e = 0; e < 8; e++) { offs[e] = o; o += cnt[e]; }   // exact, no pad
        offs[8] = o;
    }
}

__global__ __launch_bounds__(256) void scatter_k(const int* __restrict__ topi,
                                                 const float* __restrict__ gates,
                                                 const int* __restrict__ offs,
                                                 int* __restrict__ curs,
                                                 int* __restrict__ ptok,
                                                 float* __restrict__ pgate,
                                                 int* __restrict__ tokp) {
    int tk = blockIdx.x * 256 + threadIdx.x;
    if (tk >= T) return;
    for (int j = 0; j < 2; j++) {
        int e = topi[tk * 2 + j];
        int slot = atomicAdd(&curs[e], 1);
        int idx = offs[e] + slot;
        ptok[idx] = tk;
        pgate[idx] = gates[tk * 2 + j];
        tokp[tk * 2 + j] = idx;
    }
}

__global__ __launch_bounds__(256) void combine_k(const float* __restrict__ x1,
                                                 const float* __restrict__ y,
                                                 const int* __restrict__ tokp,
                                                 const float* __restrict__ pgate,
                                                 float* __restrict__ out) {
    int i = blockIdx.x * 256 + threadIdx.x;   // T*Dm/4
    int tk = i >> 8, d4 = i & 255;
    int p0 = tokp[tk * 2], p1 = tokp[tk * 2 + 1];
    float g0 = pgate[p0], g1 = pgate[p1];
    float4 a = ((const float4*)(x1 + (ll)tk * Dm))[d4];
    float4 y0 = ((const float4*)(y + (ll)p0 * Dm))[d4];
    float4 y1 = ((const float4*)(y + (ll)p1 * Dm))[d4];
    float4 o4;
    o4.x = a.x + g0 * y0.x + g1 * y1.x;
    o4.y = a.y + g0 * y0.y + g1 * y1.y;
    o4.z = a.z + g0 * y0.z + g1 * y1.z;
    o4.w = a.w + g0 * y0.w + g1 * y1.w;
    ((float4*)(out + (ll)tk * Dm))[d4] = o4;
}

__global__ void aux_k(const int* __restrict__ cnt, const float* __restrict__ psum,
                      float* __restrict__ outp) {
    if (threadIdx.x == 0 && blockIdx.x == 0) {
        float s = 0.0f;
        for (int e = 0; e < 8; e++) s += (float)cnt[e] * psum[e];
        outp[0] = 8.0f * s * (1.0f / (2048.0f * 2048.0f));
    }
}

// ---------------- launch ----------------
extern "C" void kernel_launch(void* const* d_in, const int* in_sizes, int n_in,
                              void* d_out, int out_size, void* d_ws, size_t ws_size,
                              hipStream_t stream) {
    const float* x      = (const float*)d_in[0];
    const float* n1w    = (const float*)d_in[1];
    const float* n2w    = (const float*)d_in[2];
    const float* wq_idx = (const float*)d_in[3];
    const float* wk_idx = (const float*)d_in[4];
    const float* w_head = (const float*)d_in[5];
    const float* wq     = (const float*)d_in[6];
    const float* wk     = (const float*)d_in[7];
    const float* wvp    = (const float*)d_in[8];
    const float* wo     = (const float*)d_in[9];
    const float* rw     = (const float*)d_in[10];
    const float* rb     = (const float*)d_in[11];
    const float* w1     = (const float*)d_in[12];
    const float* b1     = (const float*)d_in[13];
    const float* w2     = (const float*)d_in[14];
    const float* b2     = (const float*)d_in[15];

    float* ws = (float*)d_ws;
    float* out  = (float*)d_out;               // [T*Dm]
    float* auxp = out + (ll)T * Dm;            // [1]
    float* idxs = auxp + 1;                    // [T*T]

    float* xn   = ws + OFF_XN;
    float* qb   = ws + OFF_Q;
    float* kb   = ws + OFF_K;
    float* vb   = ws + OFF_V;
    float* av   = ws + OFF_AV;
    float* x1   = ws + OFF_X1;
    float* x2n  = ws + OFF_X2N;
    float* qi   = ws + OFF_QI;
    float* kib  = ws + OFF_KI;
    float* hwb  = ws + OFF_HW;
    float* probs = ws + OFF_PROBS;
    float* gates = ws + OFF_GATES;
    int*   topi  = (int*)(ws + OFF_TOPI);
    int*   ptok  = (int*)(ws + OFF_PTOK);
    float* pgate = ws + OFF_PGATE;
    int*   tokp  = (int*)(ws + OFF_TOKP);
    int*   cnt   = (int*)(ws + OFF_CNT);
    float* psum  = ws + OFF_PSUM;
    int*   offs  = (int*)(ws + OFF_OFFS);
    int*   curs  = (int*)(ws + OFF_CURS);
    int*   seli  = (int*)(ws + OFF_SELI);
    int*   selc  = (int*)(ws + OFF_SELC);
    // plane aliases
    ushort_t* P1H = (ushort_t*)(ws + OFF_P1H);
    ushort_t* P1M = (ushort_t*)(ws + OFF_P1M);
    ushort_t* P1L = (ushort_t*)(ws + OFF_P1L);
    ushort_t* P2H = (ushort_t*)(ws + OFF_P2H);
    ushort_t* P2M = (ushort_t*)(ws + OFF_P2M);
    ushort_t* P2L = (ushort_t*)(ws + OFF_P2L);
    ushort_t* XpH = (ushort_t*)(ws + OFF_XPH);
    ushort_t* XpM = (ushort_t*)(ws + OFF_XPM);
    ushort_t* HpH = (ushort_t*)(ws + OFF_HPH);
    ushort_t* HpM = (ushort_t*)(ws + OFF_HPM);
    float*    yb  = ws + OFF_Y2;

    hipMemsetAsync(ws + OFF_CNT, 0, 256, stream);

    // --- norm1 + xn planes ---
    rmsnorm_k<<<T, 256, 0, stream>>>(x, n1w, xn);
    splitp_k<3><<<T * Dm / 1024, 256, 0, stream>>>(xn, P1H, P1M, P1L);
    // --- indexer projections (fp32, bit-stable top-512 path) ---
    gemm_k<<<dim3(4, 16, 1), 256, 0, stream>>>(xn, Dm, wq_idx, 256, 0, qi, 256,
        nullptr, 0, nullptr, nullptr, nullptr, nullptr, 256, Dm, 0);
    gemm_k<<<dim3(1, 16, 1), 256, 0, stream>>>(xn, Dm, wk_idx, 64, 0, kib, 64,
        nullptr, 0, nullptr, nullptr, nullptr, nullptr, 64, Dm, 0);
    smalln_k<<<T / 4, 256, 0, stream>>>(xn, w_head, hwb, 4);
    // --- QKV: fused multi-B, pre-split A (bit-identical products to NS=3 mgemm) ---
    pgemm3_k<<<dim3(8, 16, 3), 256, 0, stream>>>(P1H, P1M, P1L, Dm, wq, Dm, wk, wvp,
        (ll)T * Dm, qb, Dm, nullptr, Dm, Dm, 0);
    rope_k<<<4096, 256, 0, stream>>>(qb, kb);
    // --- indexer scores + top-512 ---
    idx_k<<<dim3(32, 32, 1), 256, 0, stream>>>(qi, kib, hwb, idxs);
    topk_k<<<T, 256, 0, stream>>>(idxs, seli, selc);
    // --- sparse attention ---
    attn_k<<<T, 256, 0, stream>>>(qb, kb, vb, seli, selc, av);
    // --- wo + residual (pre-split av) ---
    splitp_k<3><<<T * Dm / 1024, 256, 0, stream>>>(av, P2H, P2M, P2L);
    pgemm3_k<<<dim3(8, 16, 1), 256, 0, stream>>>(P2H, P2M, P2L, Dm, wo, Dm, nullptr, nullptr,
        0, x1, Dm, x, Dm, Dm, 4);
    // --- norm2 + router ---
    rmsnorm_k<<<T, 256, 0, stream>>>(x1, n2w, x2n);
    router_k<<<T / 4, 256, 0, stream>>>(x2n, rw, rb, probs, gates, topi, cnt, psum);
    offs_k<<<1, 64, 0, stream>>>(cnt, offs);
    scatter_k<<<T / 256, 256, 0, stream>>>(topi, gates, offs, curs, ptok, pgate, tokp);
    // --- MoE: pre-split x2n, 2-plane A x single-plane-B MFMA GEMMs ---
    splitp_k<2><<<T * Dm / 1024, 256, 0, stream>>>(x2n, XpH, XpM, nullptr);
    for (int c = 0; c < DFF / MCH; c++) {
        // hmid planes = split(gelu(x2n[gather] @ w1c + b1))
        pgemm2_k<<<dim3(MCH / 128, 16, 8), 256, 0, stream>>>(
            XpH, XpM, Dm, w1 + c * MCH, DFF, (ll)Dm * DFF,
            nullptr, 0, HpH, HpM, MCH, b1 + c * MCH, DFF,
            ptok, cnt, offs, MCH, Dm, 3);
        // y (+)= hmid @ w2c  (+ b2 on first chunk)
        pgemm2_k<<<dim3(Dm / 128, 16, 8), 256, 0, stream>>>(
            HpH, HpM, MCH, w2 + (ll)c * MCH * Dm, Dm, (ll)DFF * Dm,
            yb, Dm, nullptr, nullptr, 0, b2, Dm,
            nullptr, cnt, offs, Dm, MCH, (c == 0) ? 1 : 8);
    }
    // --- combine + aux ---
    combine_k<<<T * Dm / 4 / 256, 256, 0, stream>>>(x1, yb, tokp, pgate, out);
    aux_k<<<1, 64, 0, stream>>>(cnt, psum, auxp);
}